// Round 17
// baseline (284.772 us; speedup 1.0000x reference)
//
#include <hip/hip_runtime.h>
#include <hip/hip_bf16.h>

namespace {

using frag_t    = __attribute__((ext_vector_type(8))) short;   // 8 bf16 = 16 B
using f32x4     = __attribute__((ext_vector_type(4))) float;   // MFMA acc
using float4_t  = __attribute__((ext_vector_type(4))) float;

constexpr int BATCH = 32;
constexpr int CIN   = 64;
constexpr int HWD   = 56;
constexpr int KOUT  = 128;
constexpr int SP    = HWD * HWD;        // 3136 = 49*64
constexpr int KD    = 9 * CIN;          // 576
constexpr int BN    = 64;               // spatial tile (divides SP)
constexpr int HALO  = 57;
constexpr int WINR  = BN + 2 * HALO;    // 178 valid staged rows
constexpr int NSTA  = 192;              // allocated rows (24 KB); 184-191 zeroed
constexpr int NT    = SP / BN;          // 49
constexpr int NWG   = NT * BATCH;       // 1568 conv blocks
constexpr int TT    = BATCH * (SP / 64);            // 1568 transpose blocks
constexpr int WB2   = (KOUT * KD) / 256;            // 288 weight blocks
constexpr int GRID  = WB2 + TT + NWG;               // 3424
constexpr int KHSTR = 18 * 2048;                    // wpA2 kh stride (ushorts)

__device__ inline unsigned short f2bf(float f) {
    __hip_bfloat16 h = __float2bfloat16(f);
    return __builtin_bit_cast(unsigned short, h);
}

// Fused producer-consumer kernel.
// Roles by blockIdx: [0,WB2) weight repack; [WB2,WB2+TT) x-transpose; rest conv.
// flags[0..31] = per-image transpose-complete counters (49 each); flags[32] = weights (288).
__global__ __launch_bounds__(256, 4)
void fused_kernel(const float* __restrict__ x, const float* __restrict__ w,
                  unsigned short* __restrict__ wpA2, unsigned short* __restrict__ xT,
                  const float* __restrict__ off, float* __restrict__ out,
                  unsigned* __restrict__ flags)
{
    __shared__ unsigned short xs[NSTA * 64];   // 24 KB (transpose role reuses as f32 ls)

    const int bid  = blockIdx.x;
    const int tid  = threadIdx.x;
    const int lane = tid & 63;
    const int wid  = tid >> 6;

    if (bid < WB2) {
        // ---------------- weight repack (producer) ----------------
        const int idx = bid * 256 + tid;                 // < 73728
        const int q   = idx & 7;
        int r1 = idx >> 3;
        const int l  = r1 & 63;  r1 >>= 6;
        const int mi = r1 & 3;   r1 >>= 2;
        const int kc = r1 % 18;
        const int kh = r1 / 18;
        const int kout = kh * 64 + mi * 16 + (l & 15);
        const int kk   = kc * 32 + (l >> 4) * 8 + q;
        const int c = kk & 63, t = kk >> 6, ky = t / 3, kx = t - ky * 3;
        wpA2[idx] = f2bf(w[((kout * CIN + c) * 3 + ky) * 3 + kx]);
        __syncthreads();
        __threadfence();
        if (tid == 0)
            __hip_atomic_fetch_add(&flags[32], 1u, __ATOMIC_RELEASE,
                                   __HIP_MEMORY_SCOPE_AGENT);
        return;
    }

    if (bid < WB2 + TT) {
        // ---------------- x transpose (producer), conv-consumption image order ----------------
        const int p    = bid - WB2;
        const int u    = p / 49;                // virtual image slot
        const int tile = p - u * 49;
        const int img  = (u & 7) * 4 + (u >> 3);// images emitted 0,4,8,...,28,1,5,...
        const int sp0  = tile * 64;
        float (*ls)[68] = reinterpret_cast<float (*)[68]>(xs);   // 64*68*4 = 17.4 KB

        const int cq  = tid >> 4;
        const int spo = (tid & 15) * 4;
        const float* xb = x + (size_t)img * CIN * SP;
        #pragma unroll
        for (int j = 0; j < 4; ++j) {
            const int c = cq + 16 * j;
            float4_t v = *(const float4_t*)&xb[(size_t)c * SP + sp0 + spo];
            ls[spo + 0][c] = v.x; ls[spo + 1][c] = v.y;
            ls[spo + 2][c] = v.z; ls[spo + 3][c] = v.w;
        }
        __syncthreads();
        unsigned short* xo = xT + (size_t)(img * SP + sp0) * 64;
        #pragma unroll
        for (int j = 0; j < 2; ++j) {
            const int s  = tid + 256 * j;
            const int sp = s >> 3, e = s & 7;
            frag_t uvec;
            #pragma unroll
            for (int q = 0; q < 8; ++q)
                uvec[q] = (short)f2bf(ls[sp][e * 8 + q]);
            *(frag_t*)&xo[sp * 64 + e * 8] = uvec;
        }
        __syncthreads();
        __threadfence();
        if (tid == 0)
            __hip_atomic_fetch_add(&flags[img], 1u, __ATOMIC_RELEASE,
                                   __HIP_MEMORY_SCOPE_AGENT);
        return;
    }

    // ---------------- conv (consumer) — R14 conv_b2 verbatim + spin-wait ----------------
    const int d    = bid - (WB2 + TT);
    const int wk   = (d & 7) * (NWG / 8) + (d >> 3);   // bijective XCD swizzle
    const int b    = wk / NT;
    const int sp0  = (wk - b * NT) * BN;

    if (tid == 0) {
        while (__hip_atomic_load(&flags[32], __ATOMIC_ACQUIRE,
                                 __HIP_MEMORY_SCOPE_AGENT) < (unsigned)WB2)
            __builtin_amdgcn_s_sleep(2);
        while (__hip_atomic_load(&flags[b], __ATOMIC_ACQUIRE,
                                 __HIP_MEMORY_SCOPE_AGENT) < 49u)
            __builtin_amdgcn_s_sleep(2);
    }
    __syncthreads();

    {
        const unsigned short* xb = xT + (size_t)b * SP * 64;
        const int lsw = ((lane & 7) * 8) ^ ((lane >> 3) << 3);
        #pragma unroll
        for (int it = 0; it < 6; ++it) {
            const int R0 = it * 32 + wid * 8;
            const int r  = R0 + (lane >> 3);
            if (r < WINR) {
                int g = sp0 - HALO + r;
                g = min(max(g, 0), SP - 1);
                __builtin_amdgcn_global_load_lds(
                    (const __attribute__((address_space(1))) unsigned int*)
                        (xb + (size_t)g * 64 + lsw),
                    (__attribute__((address_space(3))) unsigned int*)
                        &xs[R0 * 64 + lane * 8],
                    16, 0, 0);
            }
        }
        *(unsigned int*)&xs[184 * 64 + tid * 2] = 0u;   // rows 184-191 = zeros
    }
    asm volatile("s_waitcnt vmcnt(0)" ::: "memory");
    __syncthreads();

    const int l15 = lane & 15;
    const int l4  = lane >> 4;
    const int cread = 8 * l4;
    const int zaddr = 184 * 64 + cread;

    unsigned long long mbits = 0ull;
    int yv[4], xv[4];
    #pragma unroll
    for (int nf = 0; nf < 4; ++nf) {
        const int sp = sp0 + nf * 16 + l15;
        yv[nf] = sp / HWD;
        xv[nf] = sp - yv[nf] * HWD;
    }
    #pragma unroll
    for (int t = 0; t < 9; ++t) {
        const int dy = t / 3 - 1, dx = t % 3 - 1;
        #pragma unroll
        for (int nf = 0; nf < 4; ++nf) {
            const bool v = ((unsigned)(yv[nf] + dy) < (unsigned)HWD) &
                           ((unsigned)(xv[nf] + dx) < (unsigned)HWD);
            mbits |= (unsigned long long)(v ? 1 : 0) << (t * 4 + nf);
        }
    }

    const unsigned short* ap = wpA2 + (size_t)(wid >> 1) * KHSTR
                                    + (wid & 1) * 1024 + lane * 8;
    f32x4 acc[2][4] = {};

    #pragma unroll
    for (int p = 0; p < 6; ++p) {
        frag_t aB[6];
        #pragma unroll
        for (int j = 0; j < 3; ++j)
            #pragma unroll
            for (int m = 0; m < 2; ++m)
                aB[j * 2 + m] = *(const frag_t*)(ap + (size_t)(p * 3 + j) * 2048 + m * 512);
        #pragma unroll
        for (int j = 0; j < 3; ++j) {
            const int kc = p * 3 + j;
            const int t  = kc >> 1;
            const int c0 = (kc & 1) * 32;
            const int shift = (t / 3 - 1) * HWD + (t % 3 - 1);
            const int row0b = l15 + HALO + shift;
            const int sw    = (row0b & 7) << 3;
            const int cadr  = (c0 + cread) ^ sw;
            const unsigned m4 = (unsigned)((mbits >> (t * 4)) & 15ull);
            frag_t bfr[4];
            #pragma unroll
            for (int nf = 0; nf < 4; ++nf) {
                const int ba = (row0b + 16 * nf) * 64 + cadr;
                const int ra = ((m4 >> nf) & 1u) ? ba : zaddr;
                bfr[nf] = *(const frag_t*)&xs[ra];
            }
            #pragma unroll
            for (int m = 0; m < 2; ++m)
                #pragma unroll
                for (int nf = 0; nf < 4; ++nf)
                    acc[m][nf] = __builtin_amdgcn_mfma_f32_16x16x32_bf16(
                        aB[j * 2 + m], bfr[nf], acc[m][nf], 0, 0, 0);
        }
    }

    const int spn = sp0 + l15;
    #pragma unroll
    for (int m = 0; m < 2; ++m) {
        const int km = wid * 32 + m * 16 + 4 * l4;
        #pragma unroll
        for (int reg = 0; reg < 4; ++reg) {
            const int  kk  = km + reg;
            const float ofv = off[kk];
            float* ob = out + (size_t)(b * KOUT + kk) * SP;
            #pragma unroll
            for (int nf = 0; nf < 4; ++nf)
                ob[spn + 16 * nf] = acc[m][nf][reg] + ofv;
        }
    }
}

// ---- fallback: round-1 fp32 direct conv ----
__global__ __launch_bounds__(256)
void conv3x3_kernel(const float* __restrict__ x, const float* __restrict__ w,
                    const float* __restrict__ off, float* __restrict__ out)
{
    const int s  = blockIdx.x * 256 + threadIdx.x;
    const int b  = s / SP;
    const int sp = s - b * SP;
    const int y  = sp / HWD;
    const int xx = sp - y * HWD;
    const int k0 = blockIdx.y * 4;

    const int   xm1 = (xx > 0) ? xx - 1 : 0;
    const int   xp1 = (xx < HWD - 1) ? xx + 1 : HWD - 1;
    const float m0  = (xx > 0) ? 1.f : 0.f;
    const float m2  = (xx < HWD - 1) ? 1.f : 0.f;

    int ro[3]; float msk[3][3];
    #pragma unroll
    for (int ky = 0; ky < 3; ++ky) {
        const int  yy = y + ky - 1;
        const bool ok = (unsigned)yy < (unsigned)HWD;
        const float rm = ok ? 1.f : 0.f;
        ro[ky] = (ok ? yy : 0) * HWD;
        msk[ky][0] = rm * m0; msk[ky][1] = rm; msk[ky][2] = rm * m2;
    }
    float acc[4] = {0.f, 0.f, 0.f, 0.f};
    const float* xb = x + (size_t)b * CIN * SP;
    for (int c = 0; c < CIN; ++c) {
        const float* xc = xb + (size_t)c * SP;
        #pragma unroll
        for (int ky = 0; ky < 3; ++ky) {
            const float* xr = xc + ro[ky];
            const float v0 = xr[xm1] * msk[ky][0];
            const float v1 = xr[xx]  * msk[ky][1];
            const float v2 = xr[xp1] * msk[ky][2];
            const int wi = c * 9 + ky * 3;
            #pragma unroll
            for (int kk = 0; kk < 4; ++kk) {
                const float* wr = w + (size_t)(k0 + kk) * (CIN * 9) + wi;
                acc[kk] = fmaf(v0, wr[0], acc[kk]);
                acc[kk] = fmaf(v1, wr[1], acc[kk]);
                acc[kk] = fmaf(v2, wr[2], acc[kk]);
            }
        }
    }
    #pragma unroll
    for (int kk = 0; kk < 4; ++kk)
        out[(size_t)(b * KOUT + k0 + kk) * SP + sp] = acc[kk] + off[k0 + kk];
}

} // namespace

extern "C" void kernel_launch(void* const* d_in, const int* in_sizes, int n_in,
                              void* d_out, int out_size, void* d_ws, size_t ws_size,
                              hipStream_t stream)
{
    const float* x   = (const float*)d_in[0];
    const float* w   = (const float*)d_in[1];
    const float* off = (const float*)d_in[2];
    float* out = (float*)d_out;

    const size_t wpa_bytes = (size_t)KOUT * KD * 2;          // 147456
    const size_t xt_bytes  = (size_t)BATCH * SP * CIN * 2;   // 12845056
    const size_t flags_off = wpa_bytes + xt_bytes;           // 12992512 (64B aligned)

    if (ws_size >= flags_off + 256) {
        unsigned short* wpA2 = (unsigned short*)d_ws;
        unsigned short* xT   = (unsigned short*)((char*)d_ws + wpa_bytes);
        unsigned*       flg  = (unsigned*)((char*)d_ws + flags_off);
        hipMemsetAsync(flg, 0, 256, stream);                 // reset sync flags each call
        fused_kernel<<<GRID, dim3(256, 1, 1), 0, stream>>>(x, w, wpA2, xT, off, out, flg);
    } else {
        dim3 grid((BATCH * SP) / 256, KOUT / 4);
        conv3x3_kernel<<<grid, dim3(256, 1, 1), 0, stream>>>(x, w, off, out);
    }
}

// Round 18
// 39.927 us; speedup vs baseline: 7.1323x; 7.1323x over previous
//
#include <hip/hip_runtime.h>
#include <hip/hip_bf16.h>

namespace {

using frag_t    = __attribute__((ext_vector_type(8))) short;   // 8 bf16 = 16 B
using f32x4     = __attribute__((ext_vector_type(4))) float;   // MFMA acc
using float4_t  = __attribute__((ext_vector_type(4))) float;

constexpr int BATCH = 32;
constexpr int CIN   = 64;
constexpr int HWD   = 56;
constexpr int KOUT  = 128;
constexpr int SP    = HWD * HWD;        // 3136 = 49*64
constexpr int KD    = 9 * CIN;          // 576
constexpr int BN    = 64;               // spatial tile (divides SP)
constexpr int HALO  = 57;
constexpr int WINR  = BN + 2 * HALO;    // 178 valid staged rows
constexpr int NSTA  = 192;              // allocated rows (24 KB); 184-191 zeroed
constexpr int NT    = SP / BN;          // 49
constexpr int NWG   = NT * BATCH;       // 1568 = 8 * 196 (full kout per block)
constexpr int TT    = BATCH * (SP / 64);            // 1568 transpose blocks
constexpr int WB2   = (KOUT * KD) / 256;            // 288 weight blocks
constexpr int KHSTR = 18 * 2048;                    // wpA2 kh stride (ushorts)

__device__ inline unsigned short f2bf(float f) {
    __hip_bfloat16 h = __float2bfloat16(f);
    return __builtin_bit_cast(unsigned short, h);
}

// ---- prep: (a) transpose x -> xT[b][sp][c] bf16; (b) repack w lane-ordered ----
// wpA2[kh][kc][mi][lane][8]: lane l: kout = kh*64 + mi*16 + (l&15),
// kk = kc*32 + (l>>4)*8 + q   (verified R11-R15)
__global__ __launch_bounds__(256)
void prep_kernel(const float* __restrict__ x, const float* __restrict__ w,
                 unsigned short* __restrict__ wpA2, unsigned short* __restrict__ xT)
{
    if (blockIdx.x >= TT) {
        const int idx = (blockIdx.x - TT) * 256 + threadIdx.x;   // < 73728
        const int q   = idx & 7;
        int r1 = idx >> 3;
        const int l  = r1 & 63;  r1 >>= 6;
        const int mi = r1 & 3;   r1 >>= 2;
        const int kc = r1 % 18;
        const int kh = r1 / 18;
        const int kout = kh * 64 + mi * 16 + (l & 15);
        const int kk   = kc * 32 + (l >> 4) * 8 + q;
        const int c = kk & 63, t = kk >> 6, ky = t / 3, kx = t - ky * 3;
        wpA2[idx] = f2bf(w[((kout * CIN + c) * 3 + ky) * 3 + kx]);
        return;
    }
    __shared__ float ls[64][68];
    const int bb   = blockIdx.x / (SP / 64);
    const int tile = blockIdx.x - bb * (SP / 64);
    const int sp0  = tile * 64;
    const int tid  = threadIdx.x;
    const int cq   = tid >> 4;
    const int spo  = (tid & 15) * 4;
    const float* xb = x + (size_t)bb * CIN * SP;
    #pragma unroll
    for (int j = 0; j < 4; ++j) {
        const int c = cq + 16 * j;
        float4_t v = *(const float4_t*)&xb[(size_t)c * SP + sp0 + spo];
        ls[spo + 0][c] = v.x; ls[spo + 1][c] = v.y;
        ls[spo + 2][c] = v.z; ls[spo + 3][c] = v.w;
    }
    __syncthreads();
    unsigned short* xo = xT + (size_t)(bb * SP + sp0) * 64;
    #pragma unroll
    for (int j = 0; j < 2; ++j) {
        const int s  = tid + 256 * j;
        const int sp = s >> 3, e = s & 7;
        frag_t u;
        #pragma unroll
        for (int q = 0; q < 8; ++q)
            u[q] = (short)f2bf(ls[sp][e * 8 + q]);
        *(frag_t*)&xo[sp * 64 + e * 8] = u;
    }
}

// ---- conv: full-kout block, mi=2 x nf=4 waves, A reg-batched, no K-loop barriers ----
__global__ __launch_bounds__(256, 4)
void conv_b2(const unsigned short* __restrict__ xT, const unsigned short* __restrict__ wpA2,
             const float* __restrict__ off, float* __restrict__ out)
{
    // xs[row][c] bf16; slot [r][z] holds xT[g(r)][z ^ ((r&7)<<3)]; rows 184-191 = 0
    __shared__ unsigned short xs[NSTA * 64];   // 24 KB

    const int d    = blockIdx.x;
    const int wk   = (d & 7) * (NWG / 8) + (d >> 3);   // bijective XCD swizzle
    const int b    = wk / NT;
    const int sp0  = (wk - b * NT) * BN;
    const int tid  = threadIdx.x;
    const int lane = tid & 63;
    const int wid  = tid >> 6;

    // ---------- stage 178-row window once (shared by all 128 kouts) ----------
    {
        const unsigned short* xb = xT + (size_t)b * SP * 64;
        const int lsw = ((lane & 7) * 8) ^ ((lane >> 3) << 3);
        #pragma unroll
        for (int it = 0; it < 6; ++it) {
            const int R0 = it * 32 + wid * 8;       // wave-uniform base row
            const int r  = R0 + (lane >> 3);
            if (r < WINR) {
                int g = sp0 - HALO + r;
                g = min(max(g, 0), SP - 1);
                __builtin_amdgcn_global_load_lds(
                    (const __attribute__((address_space(1))) unsigned int*)
                        (xb + (size_t)g * 64 + lsw),
                    (__attribute__((address_space(3))) unsigned int*)
                        &xs[R0 * 64 + lane * 8],
                    16, 0, 0);
            }
        }
        *(unsigned int*)&xs[184 * 64 + tid * 2] = 0u;   // rows 184-191 = zeros
    }
    asm volatile("s_waitcnt vmcnt(0)" ::: "memory");
    __syncthreads();

    const int l15 = lane & 15;
    const int l4  = lane >> 4;
    const int cread = 8 * l4;
    const int zaddr = 184 * 64 + cread;        // zero-row read address

    // ---------- per-(tap, nf) validity masks (bit t*4+nf) ----------
    unsigned long long mbits = 0ull;
    int yv[4], xv[4];
    #pragma unroll
    for (int nf = 0; nf < 4; ++nf) {
        const int sp = sp0 + nf * 16 + l15;
        yv[nf] = sp / HWD;
        xv[nf] = sp - yv[nf] * HWD;
    }
    #pragma unroll
    for (int t = 0; t < 9; ++t) {
        const int dy = t / 3 - 1, dx = t % 3 - 1;
        #pragma unroll
        for (int nf = 0; nf < 4; ++nf) {
            const bool v = ((unsigned)(yv[nf] + dy) < (unsigned)HWD) &
                           ((unsigned)(xv[nf] + dx) < (unsigned)HWD);
            mbits |= (unsigned long long)(v ? 1 : 0) << (t * 4 + nf);
        }
    }

    // wave's A base: kouts wid*32 .. wid*32+31  (kh = wid>>1, mi_local = (wid&1)*2+m)
    const unsigned short* ap = wpA2 + (size_t)(wid >> 1) * KHSTR
                                    + (wid & 1) * 1024 + lane * 8;
    f32x4 acc[2][4] = {};              // [m][nf]

    // ---------- K loop: 6 batches x 3 kc; A batched into regs (6 indep loads) ----------
    #pragma unroll
    for (int p = 0; p < 6; ++p) {
        frag_t aB[6];
        #pragma unroll
        for (int j = 0; j < 3; ++j)
            #pragma unroll
            for (int m = 0; m < 2; ++m)
                aB[j * 2 + m] = *(const frag_t*)(ap + (size_t)(p * 3 + j) * 2048 + m * 512);
        #pragma unroll
        for (int j = 0; j < 3; ++j) {
            const int kc = p * 3 + j;
            const int t  = kc >> 1;
            const int c0 = (kc & 1) * 32;
            const int shift = (t / 3 - 1) * HWD + (t % 3 - 1);
            const int row0b = l15 + HALO + shift;      // in [0,129]; low3 nf-invariant
            const int sw    = (row0b & 7) << 3;
            const int cadr  = (c0 + cread) ^ sw;
            const unsigned m4 = (unsigned)((mbits >> (t * 4)) & 15ull);
            frag_t bfr[4];
            #pragma unroll
            for (int nf = 0; nf < 4; ++nf) {
                const int ba = (row0b + 16 * nf) * 64 + cadr;
                const int ra = ((m4 >> nf) & 1u) ? ba : zaddr;   // zero-row redirect
                bfr[nf] = *(const frag_t*)&xs[ra];
            }
            #pragma unroll
            for (int m = 0; m < 2; ++m)
                #pragma unroll
                for (int nf = 0; nf < 4; ++nf)
                    acc[m][nf] = __builtin_amdgcn_mfma_f32_16x16x32_bf16(
                        aB[j * 2 + m], bfr[nf], acc[m][nf], 0, 0, 0);
        }
    }

    // ---------- epilogue (BN divides SP: no guards) ----------
    const int spn = sp0 + l15;
    #pragma unroll
    for (int m = 0; m < 2; ++m) {
        const int km = wid * 32 + m * 16 + 4 * l4;
        #pragma unroll
        for (int reg = 0; reg < 4; ++reg) {
            const int  kk  = km + reg;
            const float ofv = off[kk];
            float* ob = out + (size_t)(b * KOUT + kk) * SP;
            #pragma unroll
            for (int nf = 0; nf < 4; ++nf)
                ob[spn + 16 * nf] = acc[m][nf][reg] + ofv;
        }
    }
}

// ---- fallback: round-1 fp32 direct conv ----
__global__ __launch_bounds__(256)
void conv3x3_kernel(const float* __restrict__ x, const float* __restrict__ w,
                    const float* __restrict__ off, float* __restrict__ out)
{
    const int s  = blockIdx.x * 256 + threadIdx.x;
    const int b  = s / SP;
    const int sp = s - b * SP;
    const int y  = sp / HWD;
    const int xx = sp - y * HWD;
    const int k0 = blockIdx.y * 4;

    const int   xm1 = (xx > 0) ? xx - 1 : 0;
    const int   xp1 = (xx < HWD - 1) ? xx + 1 : HWD - 1;
    const float m0  = (xx > 0) ? 1.f : 0.f;
    const float m2  = (xx < HWD - 1) ? 1.f : 0.f;

    int ro[3]; float msk[3][3];
    #pragma unroll
    for (int ky = 0; ky < 3; ++ky) {
        const int  yy = y + ky - 1;
        const bool ok = (unsigned)yy < (unsigned)HWD;
        const float rm = ok ? 1.f : 0.f;
        ro[ky] = (ok ? yy : 0) * HWD;
        msk[ky][0] = rm * m0; msk[ky][1] = rm; msk[ky][2] = rm * m2;
    }
    float acc[4] = {0.f, 0.f, 0.f, 0.f};
    const float* xb = x + (size_t)b * CIN * SP;
    for (int c = 0; c < CIN; ++c) {
        const float* xc = xb + (size_t)c * SP;
        #pragma unroll
        for (int ky = 0; ky < 3; ++ky) {
            const float* xr = xc + ro[ky];
            const float v0 = xr[xm1] * msk[ky][0];
            const float v1 = xr[xx]  * msk[ky][1];
            const float v2 = xr[xp1] * msk[ky][2];
            const int wi = c * 9 + ky * 3;
            #pragma unroll
            for (int kk = 0; kk < 4; ++kk) {
                const float* wr = w + (size_t)(k0 + kk) * (CIN * 9) + wi;
                acc[kk] = fmaf(v0, wr[0], acc[kk]);
                acc[kk] = fmaf(v1, wr[1], acc[kk]);
                acc[kk] = fmaf(v2, wr[2], acc[kk]);
            }
        }
    }
    #pragma unroll
    for (int kk = 0; kk < 4; ++kk)
        out[(size_t)(b * KOUT + k0 + kk) * SP + sp] = acc[kk] + off[k0 + kk];
}

} // namespace

extern "C" void kernel_launch(void* const* d_in, const int* in_sizes, int n_in,
                              void* d_out, int out_size, void* d_ws, size_t ws_size,
                              hipStream_t stream)
{
    const float* x   = (const float*)d_in[0];
    const float* w   = (const float*)d_in[1];
    const float* off = (const float*)d_in[2];
    float* out = (float*)d_out;

    const size_t wpa_bytes = (size_t)KOUT * KD * 2;          // 147456
    const size_t xt_bytes  = (size_t)BATCH * SP * CIN * 2;   // 12845056

    if (ws_size >= wpa_bytes + xt_bytes) {
        unsigned short* wpA2 = (unsigned short*)d_ws;
        unsigned short* xT   = (unsigned short*)((char*)d_ws + wpa_bytes);
        prep_kernel<<<TT + WB2, 256, 0, stream>>>(x, w, wpA2, xT);
        conv_b2<<<NWG, dim3(256, 1, 1), 0, stream>>>(xT, wpA2, off, out);
    } else {
        dim3 grid((BATCH * SP) / 256, KOUT / 4);
        conv3x3_kernel<<<grid, dim3(256, 1, 1), 0, stream>>>(x, w, off, out);
    }
}